// Round 10
// baseline (900.965 us; speedup 1.0000x reference)
//
#include <hip/hip_runtime.h>

// Problem constants (fixed by reference)
#define R_   3
#define N_   50000
#define E_   400000
#define IN_  128
#define HID_ 64
#define C_   40
#define H_   3
#define NEG_SLOPE 0.2f

#define SCAN_CHUNK 1024
#define NCH  49      // ceil(N_/1024)
#define NCH2 64      // padded stride

typedef _Float16 half_t;
typedef _Float16 f16x8 __attribute__((ext_vector_type(8)));
typedef _Float16 f16x4 __attribute__((ext_vector_type(4)));
typedef float float4v __attribute__((ext_vector_type(4)));

template <int V> struct vecT;
template <> struct vecT<4> { typedef f16x4 type; };
template <> struct vecT<8> { typedef f16x8 type; };

// ---------------- utility ----------------
__global__ void zero_kernel(float* __restrict__ p, size_t n) {
    size_t i = (size_t)blockIdx.x * blockDim.x + threadIdx.x;
    if (i < n) p[i] = 0.f;
}

// float -> half, vectorized x4 (n must be divisible by 4)
__global__ void cast_f2h_kernel(const float* __restrict__ in, half_t* __restrict__ outp, int n4) {
    int i = blockIdx.x * 256 + threadIdx.x;
    if (i < n4) {
        float4 v = ((const float4*)in)[i];
        f16x4 h;
        h[0] = (half_t)v.x; h[1] = (half_t)v.y;
        h[2] = (half_t)v.z; h[3] = (half_t)v.w;
        ((f16x4*)outp)[i] = h;
    }
}

// W: [R][K][Nc] fp32 -> Wt: [R][Nc][K] fp16 (tiny matrices)
__global__ void transcast_kernel(const float* __restrict__ W, half_t* __restrict__ Wt,
                                 int K, int Nc) {
    int idx = blockIdx.x * 256 + threadIdx.x;
    int total = R_ * K * Nc;
    if (idx < total) {
        int r = idx / (K * Nc);
        int rem = idx - r * K * Nc;
        int n = rem / K;
        int k = rem - n * K;
        Wt[idx] = (half_t)W[((size_t)r * K + k) * Nc + n];
    }
}

// ---------------- CSR build ----------------
__global__ void hist_kernel(const int* __restrict__ dst, int* __restrict__ deg) {
    int idx = blockIdx.x * 256 + threadIdx.x;
    if (idx < R_ * E_) {
        int r = idx / E_;
        atomicAdd(&deg[r * N_ + dst[idx]], 1);
    }
}

__global__ void scanA_kernel(const int* __restrict__ deg, int* __restrict__ bsum) {
    int r = blockIdx.y, ch = blockIdx.x, tid = threadIdx.x;
    int base = ch * SCAN_CHUNK + tid * 4;
    int s = 0;
    for (int j = 0; j < 4; ++j) {
        int i = base + j;
        if (i < N_) s += deg[r * N_ + i];
    }
    __shared__ int red[256];
    red[tid] = s; __syncthreads();
    for (int off = 128; off; off >>= 1) {
        if (tid < off) red[tid] += red[tid + off];
        __syncthreads();
    }
    if (tid == 0) bsum[r * NCH2 + ch] = red[0];
}

__global__ void scanB_kernel(int* __restrict__ bsum) {
    int t = threadIdx.x;
    if (t < R_) {
        int run = 0;
        for (int c = 0; c < NCH; ++c) {
            int v = bsum[t * NCH2 + c];
            bsum[t * NCH2 + c] = run;
            run += v;
        }
    }
}

__global__ void scanC_kernel(const int* __restrict__ deg, const int* __restrict__ bsum,
                             int* __restrict__ rowptr, int* __restrict__ cursor) {
    int r = blockIdx.y, ch = blockIdx.x, tid = threadIdx.x;
    int base = ch * SCAN_CHUNK + tid * 4;
    int v[4]; int s = 0;
    for (int j = 0; j < 4; ++j) {
        int i = base + j;
        v[j] = (i < N_) ? deg[r * N_ + i] : 0;
        s += v[j];
    }
    __shared__ int buf[256];
    buf[tid] = s; __syncthreads();
    for (int off = 1; off < 256; off <<= 1) {
        int t2 = (tid >= off) ? buf[tid - off] : 0;
        __syncthreads();
        buf[tid] += t2;
        __syncthreads();
    }
    int excl = buf[tid] - s + bsum[r * NCH2 + ch];
    int run = excl;
    for (int j = 0; j < 4; ++j) {
        int i = base + j;
        if (i < N_) {
            rowptr[r * (N_ + 1) + i] = run;
            cursor[r * N_ + i] = run;
            run += v[j];
        }
    }
    if (ch == 0 && tid == 0) rowptr[r * (N_ + 1) + N_] = E_;
}

__global__ void fill_kernel(const int* __restrict__ src, const int* __restrict__ dst,
                            int* __restrict__ cursor, int* __restrict__ csr_src) {
    int idx = blockIdx.x * 256 + threadIdx.x;
    if (idx < R_ * E_) {
        int r = idx / E_;
        int pos = atomicAdd(&cursor[r * N_ + dst[idx]], 1);
        csr_src[(size_t)r * E_ + pos] = src[idx];
    }
}

// ---------------- MFMA GEMM: Z[r] = A @ Bt[r]^T (row stride = Nc) ----------------
template <int K>
__global__ __launch_bounds__(256) void mfma_gemm_kernel(
        const half_t* __restrict__ A, const half_t* __restrict__ Bt,
        half_t* __restrict__ Z, int M, int Nc) {
    int r = blockIdx.z;
    int wave = threadIdx.x >> 6, lane = threadIdx.x & 63;
    int lrow = lane & 15, lq = lane >> 4;
    int rowA = blockIdx.x * 64 + wave * 16 + lrow;
    int col0 = blockIdx.y * 64;
    const half_t* Btr = Bt + (size_t)r * Nc * K;
    const half_t* aP = A + (size_t)rowA * K + lq * 8;
    bool arow_ok = (rowA < M);
    f16x8 zv8 = {};
    float4v acc[4] = {};
    #pragma unroll
    for (int k0 = 0; k0 < K; k0 += 32) {
        f16x8 af = arow_ok ? *(const f16x8*)(aP + k0) : zv8;
        #pragma unroll
        for (int ct = 0; ct < 4; ++ct) {
            int col = col0 + ct * 16 + lrow;
            f16x8 bf = (col < Nc) ? *(const f16x8*)(Btr + (size_t)col * K + lq * 8 + k0) : zv8;
            acc[ct] = __builtin_amdgcn_mfma_f32_16x16x32_f16(af, bf, acc[ct], 0, 0, 0);
        }
    }
    half_t* Zr = Z + (size_t)r * N_ * Nc;
    int rbase = blockIdx.x * 64 + wave * 16 + lq * 4;
    #pragma unroll
    for (int ct = 0; ct < 4; ++ct) {
        int col = col0 + ct * 16 + lrow;
        if (col >= Nc) continue;
        #pragma unroll
        for (int g = 0; g < 4; ++g) {
            int row = rbase + g;
            if (row < M) Zr[(size_t)row * Nc + col] = (half_t)acc[ct][g];
        }
    }
}

// ---------------- attention logits v2: one THREAD per (r,n,h), no shuffles ----
// z rows contiguous [rn][3*Dd]; thread dots its Dd-segment with al/ar (L1-
// resident), writes el[t], er[t] where t = rn*3 + h.
template <int Dd>
__global__ __launch_bounds__(256) void attn2_kernel(
        const half_t* __restrict__ z, const float* __restrict__ al,
        const float* __restrict__ ar, float* __restrict__ el,
        float* __restrict__ er) {
    int t = blockIdx.x * 256 + threadIdx.x;
    if (t >= R_ * N_ * H_) return;
    int rn = t / H_, h = t - rn * H_;
    int r = rn / N_;
    const half_t* zrow = z + (size_t)rn * (3 * Dd) + h * Dd;
    const float* alp = al + (r * H_ + h) * Dd;
    const float* arp = ar + (r * H_ + h) * Dd;
    float p0 = 0.f, p1 = 0.f, q0 = 0.f, q1 = 0.f;
    #pragma unroll
    for (int c = 0; c < Dd / 8; ++c) {
        f16x8 zv = *(const f16x8*)(zrow + c * 8);
        #pragma unroll
        for (int j = 0; j < 8; j += 2) {
            float za = (float)zv[j], zb = (float)zv[j + 1];
            p0 += za * alp[c * 8 + j];
            p1 += zb * alp[c * 8 + j + 1];
            q0 += za * arp[c * 8 + j];
            q1 += zb * arp[c * 8 + j + 1];
        }
    }
    el[t] = p0 + p1;
    er[t] = q0 + q1;
}

// ---------------- fused softmax + gather + aggregate (v6) ----------------
// agg7 main loop (split-wave, no-max softmax, 4-edge unroll, independent
// gathers) + LDS epilogue: per-wave LDS strip, ~9 independent ds_add_f32 +
// 6 reads replace the 33-op serial shuffle chain. el separate (L2-resident),
// z rows unpadded & 64B-friendly.
template <int Dd, int VEC, bool RELU>
__global__ __launch_bounds__(256) void agg9_kernel(
        const int* __restrict__ rowptr, const int* __restrict__ csr_src,
        const half_t* __restrict__ z, const float* __restrict__ el,
        const float* __restrict__ er, const float* __restrict__ bias,
        float* __restrict__ out, float scale) {
    constexpr int ROWH = 3 * Dd;        // halves per z row
    constexpr int LPE  = ROWH / VEC;    // sub-lanes per edge (30 / 24)
    constexpr int PH   = Dd / VEC;      // sub-lanes per head (10 / 8)
    using fv = typename vecT<VEC>::type;
    __shared__ float sred[4][ROWH + 4];
    int w = threadIdx.x >> 6;
    int wid = blockIdx.x * 4 + w;
    int lane = threadIdx.x & 63;
    if (wid >= R_ * N_) return;
    int r = wid / N_, n = wid - r * N_;
    int start = rowptr[r * (N_ + 1) + n];
    int end   = rowptr[r * (N_ + 1) + n + 1];
    const int* cs = csr_src + (size_t)r * E_;
    const half_t* zr = z + (size_t)r * N_ * ROWH;   // uniform base
    const float* elr = el + (size_t)r * N_ * H_;
    // zero this wave's LDS strip (independent writes, no barrier needed)
    for (int j = lane; j < ROWH + 3; j += 64) sred[w][j] = 0.f;
    int hf = lane >> 5;                 // half-wave index
    int sub = lane & 31;
    bool act = sub < LPE;
    int hl = act ? sub / PH : 0;
    int dl = act ? sub - hl * PH : 0;
    float erv = er[(size_t)wid * H_ + hl];
    int zoff = VEC * sub;
    float a[VEC] = {};
    float l = 0.f;
    int i = start;
    // main: 2 pairs (4 edges) per iteration
    for (; i + 4 <= end; i += 4) {
        int sA = cs[i + hf], sB = cs[i + 2 + hf];
        int oA = sA * ROWH, oB = sB * ROWH;
        float xA = elr[sA * H_ + hl] + erv;
        float xB = elr[sB * H_ + hl] + erv;
        fv zA = {}, zB = {};
        if (act) {
            zA = *(const fv*)(zr + oA + zoff);
            zB = *(const fv*)(zr + oB + zoff);
        }
        xA = fmaxf(xA, NEG_SLOPE * xA);
        xB = fmaxf(xB, NEG_SLOPE * xB);
        float cA = __expf(xA), cB = __expf(xB);
        l += cA + cB;
        #pragma unroll
        for (int v = 0; v < VEC; ++v)
            a[v] += cA * (float)zA[v] + cB * (float)zB[v];
    }
    // tail: guarded pairs (up to 3 edges left)
    for (; i < end; i += 2) {
        int e0 = i + hf;
        bool ok = e0 < end;
        int s0 = ok ? cs[e0] : cs[start];
        int o0 = s0 * ROWH;
        float x = elr[s0 * H_ + hl] + erv;
        fv z0 = {};
        if (act) z0 = *(const fv*)(zr + o0 + zoff);
        x = fmaxf(x, NEG_SLOPE * x);
        float c = ok ? __expf(x) : 0.f;
        l += c;
        #pragma unroll
        for (int v = 0; v < VEC; ++v)
            a[v] += c * (float)z0[v];
    }
    // ---- LDS reduce: both halves add into the wave strip ----
    if (act) {
        int ab = hl * Dd + VEC * dl;
        #pragma unroll
        for (int v = 0; v < VEC; ++v)
            atomicAdd(&sred[w][ab + v], a[v]);
        if (dl == 0) atomicAdd(&sred[w][ROWH + hl], l);
    }
    // readback (same wave — ordered by lgkmcnt, no barrier)
    if (lane < Dd) {
        float a0 = sred[w][lane];
        float a1 = sred[w][Dd + lane];
        float a2 = sred[w][2 * Dd + lane];
        float l0 = sred[w][ROWH + 0];
        float l1 = sred[w][ROWH + 1];
        float l2 = sred[w][ROWH + 2];
        float li0 = (l0 > 0.f) ? 1.f / l0 : 0.f;
        float li1 = (l1 > 0.f) ? 1.f / l1 : 0.f;
        float li2 = (l2 > 0.f) ? 1.f / l2 : 0.f;
        const float* br = bias + r * ROWH;
        float v0 = a0 * li0 + br[lane];
        float v1 = a1 * li1 + br[Dd + lane];
        float v2 = a2 * li2 + br[2 * Dd + lane];
        if (RELU) {
            v0 = fmaxf(v0, 0.f); v1 = fmaxf(v1, 0.f); v2 = fmaxf(v2, 0.f);
        }
        atomicAdd(&out[(size_t)n * Dd + lane], (v0 + v1 + v2) * scale);
    }
}

// ---------------- launch ----------------
static inline size_t align256(size_t x) { return (x + 255) & ~(size_t)255; }

extern "C" void kernel_launch(void* const* d_in, const int* in_sizes, int n_in,
                              void* d_out, int out_size, void* d_ws, size_t ws_size,
                              hipStream_t stream) {
    const float* feat = (const float*)d_in[0];
    const int*   src  = (const int*)d_in[1];
    const int*   dst  = (const int*)d_in[2];
    const float* W1   = (const float*)d_in[3];
    const float* al1  = (const float*)d_in[4];
    const float* ar1  = (const float*)d_in[5];
    const float* b1   = (const float*)d_in[6];
    const float* W2   = (const float*)d_in[7];
    const float* al2  = (const float*)d_in[8];
    const float* ar2  = (const float*)d_in[9];
    const float* b2   = (const float*)d_in[10];
    float* out = (float*)d_out;

    // workspace carve (zbuf sized for layer1: R*N*192 halves)
    char* ws = (char*)d_ws;
    size_t off = 0;
    half_t* zbuf = (half_t*)(ws + off); off += align256((size_t)R_ * N_ * (3 * HID_) * 2);
    half_t* featH = (half_t*)(ws + off); off += align256((size_t)N_ * IN_ * 2);
    half_t* h1h  = (half_t*)(ws + off); off += align256((size_t)N_ * HID_ * 2);
    half_t* W1t  = (half_t*)(ws + off); off += align256((size_t)R_ * (H_ * HID_) * IN_ * 2);
    half_t* W2t  = (half_t*)(ws + off); off += align256((size_t)R_ * (H_ * C_) * HID_ * 2);
    float* el   = (float*)(ws + off); off += align256((size_t)R_ * N_ * H_ * 4);
    float* er   = (float*)(ws + off); off += align256((size_t)R_ * N_ * H_ * 4);
    float* h1f  = (float*)(ws + off); off += align256((size_t)N_ * HID_ * 4);
    int* deg    = (int*)(ws + off);   off += align256((size_t)R_ * N_ * 4);
    int* rowptr = (int*)(ws + off);   off += align256((size_t)R_ * (N_ + 1) * 4);
    int* cursor = (int*)(ws + off);   off += align256((size_t)R_ * N_ * 4);
    int* bsum   = (int*)(ws + off);   off += align256((size_t)R_ * NCH2 * 4);
    int* csr    = (int*)(ws + off);   off += align256((size_t)R_ * E_ * 4);
    (void)ws_size; (void)n_in; (void)in_sizes; (void)out_size;

    const int EDGE_BLOCKS = (R_ * E_ + 255) / 256;     // 4688
    const int ROW_TILES = (N_ + 63) / 64;              // 782
    const int NODE_BLOCKS = (R_ * N_ + 255) / 256;     // 586
    const int WAVE_BLOCKS = (R_ * N_) / 4;             // 37500
    const int ATTN_BLOCKS = (R_ * N_ * H_ + 255) / 256;// 1758

    // ---- input casts / weight transposes ----
    cast_f2h_kernel<<<(N_ * IN_ / 4 + 255) / 256, 256, 0, stream>>>(feat, featH, N_ * IN_ / 4);
    transcast_kernel<<<(R_ * IN_ * (H_ * HID_) + 255) / 256, 256, 0, stream>>>(W1, W1t, IN_, H_ * HID_);
    transcast_kernel<<<(R_ * HID_ * (H_ * C_) + 255) / 256, 256, 0, stream>>>(W2, W2t, HID_, H_ * C_);

    // ---- CSR build (shared by both layers) ----
    zero_kernel<<<NODE_BLOCKS, 256, 0, stream>>>((float*)deg, (size_t)R_ * N_);
    hist_kernel<<<EDGE_BLOCKS, 256, 0, stream>>>(dst, deg);
    scanA_kernel<<<dim3(NCH, R_), 256, 0, stream>>>(deg, bsum);
    scanB_kernel<<<1, 64, 0, stream>>>(bsum);
    scanC_kernel<<<dim3(NCH, R_), 256, 0, stream>>>(deg, bsum, rowptr, cursor);
    fill_kernel<<<EDGE_BLOCKS, 256, 0, stream>>>(src, dst, cursor, csr);

    // ---- layer 1: IN -> H*HID, relu ----
    mfma_gemm_kernel<IN_><<<dim3(ROW_TILES, 3, R_), 256, 0, stream>>>(
        featH, W1t, zbuf, N_, H_ * HID_);
    attn2_kernel<HID_><<<ATTN_BLOCKS, 256, 0, stream>>>(zbuf, al1, ar1, el, er);
    zero_kernel<<<((size_t)N_ * HID_ + 255) / 256, 256, 0, stream>>>(h1f, (size_t)N_ * HID_);
    agg9_kernel<HID_, 8, true><<<WAVE_BLOCKS, 256, 0, stream>>>(
        rowptr, csr, zbuf, el, er, b1, h1f, 1.f / (H_ * R_));
    cast_f2h_kernel<<<(N_ * HID_ / 4 + 255) / 256, 256, 0, stream>>>(h1f, h1h, N_ * HID_ / 4);

    // ---- layer 2: HID -> H*C, no relu ----
    mfma_gemm_kernel<HID_><<<dim3(ROW_TILES, 2, R_), 256, 0, stream>>>(
        h1h, W2t, zbuf, N_, H_ * C_);
    attn2_kernel<C_><<<ATTN_BLOCKS, 256, 0, stream>>>(zbuf, al2, ar2, el, er);
    zero_kernel<<<((size_t)N_ * C_ + 255) / 256, 256, 0, stream>>>(out, (size_t)N_ * C_);
    agg9_kernel<C_, 4, false><<<WAVE_BLOCKS, 256, 0, stream>>>(
        rowptr, csr, zbuf, el, er, b2, out, 1.f / (H_ * R_));
}

// Round 12
// 573.631 us; speedup vs baseline: 1.5706x; 1.5706x over previous
//
#include <hip/hip_runtime.h>

// Problem constants (fixed by reference)
#define R_   3
#define N_   50000
#define E_   400000
#define IN_  128
#define HID_ 64
#define C_   40
#define H_   3
#define NEG_SLOPE 0.2f

#define SCAN_CHUNK 1024
#define NCH  49      // ceil(N_/1024)
#define NCH2 64      // padded stride

typedef _Float16 half_t;
typedef _Float16 f16x8 __attribute__((ext_vector_type(8)));
typedef _Float16 f16x4 __attribute__((ext_vector_type(4)));
typedef float float4v __attribute__((ext_vector_type(4)));

template <int V> struct vecT;
template <> struct vecT<4> { typedef f16x4 type; };
template <> struct vecT<8> { typedef f16x8 type; };

// ---------------- utility ----------------
__global__ void zero_kernel(float* __restrict__ p, size_t n) {
    size_t i = (size_t)blockIdx.x * blockDim.x + threadIdx.x;
    if (i < n) p[i] = 0.f;
}

// float -> half, vectorized x4 (n must be divisible by 4)
__global__ void cast_f2h_kernel(const float* __restrict__ in, half_t* __restrict__ outp, int n4) {
    int i = blockIdx.x * 256 + threadIdx.x;
    if (i < n4) {
        float4 v = ((const float4*)in)[i];
        f16x4 h;
        h[0] = (half_t)v.x; h[1] = (half_t)v.y;
        h[2] = (half_t)v.z; h[3] = (half_t)v.w;
        ((f16x4*)outp)[i] = h;
    }
}

// W: [R][K][Nc] fp32 -> Wt: [R][Nc][K] fp16 (tiny matrices)
__global__ void transcast_kernel(const float* __restrict__ W, half_t* __restrict__ Wt,
                                 int K, int Nc) {
    int idx = blockIdx.x * 256 + threadIdx.x;
    int total = R_ * K * Nc;
    if (idx < total) {
        int r = idx / (K * Nc);
        int rem = idx - r * K * Nc;
        int n = rem / K;
        int k = rem - n * K;
        Wt[idx] = (half_t)W[((size_t)r * K + k) * Nc + n];
    }
}

// ---------------- CSR build ----------------
__global__ void hist_kernel(const int* __restrict__ dst, int* __restrict__ deg) {
    int idx = blockIdx.x * 256 + threadIdx.x;
    if (idx < R_ * E_) {
        int r = idx / E_;
        atomicAdd(&deg[r * N_ + dst[idx]], 1);
    }
}

__global__ void scanA_kernel(const int* __restrict__ deg, int* __restrict__ bsum) {
    int r = blockIdx.y, ch = blockIdx.x, tid = threadIdx.x;
    int base = ch * SCAN_CHUNK + tid * 4;
    int s = 0;
    for (int j = 0; j < 4; ++j) {
        int i = base + j;
        if (i < N_) s += deg[r * N_ + i];
    }
    __shared__ int red[256];
    red[tid] = s; __syncthreads();
    for (int off = 128; off; off >>= 1) {
        if (tid < off) red[tid] += red[tid + off];
        __syncthreads();
    }
    if (tid == 0) bsum[r * NCH2 + ch] = red[0];
}

__global__ void scanB_kernel(int* __restrict__ bsum) {
    int t = threadIdx.x;
    if (t < R_) {
        int run = 0;
        for (int c = 0; c < NCH; ++c) {
            int v = bsum[t * NCH2 + c];
            bsum[t * NCH2 + c] = run;
            run += v;
        }
    }
}

__global__ void scanC_kernel(const int* __restrict__ deg, const int* __restrict__ bsum,
                             int* __restrict__ rowptr, int* __restrict__ cursor) {
    int r = blockIdx.y, ch = blockIdx.x, tid = threadIdx.x;
    int base = ch * SCAN_CHUNK + tid * 4;
    int v[4]; int s = 0;
    for (int j = 0; j < 4; ++j) {
        int i = base + j;
        v[j] = (i < N_) ? deg[r * N_ + i] : 0;
        s += v[j];
    }
    __shared__ int buf[256];
    buf[tid] = s; __syncthreads();
    for (int off = 1; off < 256; off <<= 1) {
        int t2 = (tid >= off) ? buf[tid - off] : 0;
        __syncthreads();
        buf[tid] += t2;
        __syncthreads();
    }
    int excl = buf[tid] - s + bsum[r * NCH2 + ch];
    int run = excl;
    for (int j = 0; j < 4; ++j) {
        int i = base + j;
        if (i < N_) {
            rowptr[r * (N_ + 1) + i] = run;
            cursor[r * N_ + i] = run;
            run += v[j];
        }
    }
    if (ch == 0 && tid == 0) rowptr[r * (N_ + 1) + N_] = E_;
}

__global__ void fill_kernel(const int* __restrict__ src, const int* __restrict__ dst,
                            int* __restrict__ cursor, int* __restrict__ csr_src) {
    int idx = blockIdx.x * 256 + threadIdx.x;
    if (idx < R_ * E_) {
        int r = idx / E_;
        int pos = atomicAdd(&cursor[r * N_ + dst[idx]], 1);
        csr_src[(size_t)r * E_ + pos] = src[idx];
    }
}

// ---------------- MFMA GEMM: Z[r] = A @ Bt[r]^T (row stride = Nc) ----------------
template <int K>
__global__ __launch_bounds__(256) void mfma_gemm_kernel(
        const half_t* __restrict__ A, const half_t* __restrict__ Bt,
        half_t* __restrict__ Z, int M, int Nc) {
    int r = blockIdx.z;
    int wave = threadIdx.x >> 6, lane = threadIdx.x & 63;
    int lrow = lane & 15, lq = lane >> 4;
    int rowA = blockIdx.x * 64 + wave * 16 + lrow;
    int col0 = blockIdx.y * 64;
    const half_t* Btr = Bt + (size_t)r * Nc * K;
    const half_t* aP = A + (size_t)rowA * K + lq * 8;
    bool arow_ok = (rowA < M);
    f16x8 zv8 = {};
    float4v acc[4] = {};
    #pragma unroll
    for (int k0 = 0; k0 < K; k0 += 32) {
        f16x8 af = arow_ok ? *(const f16x8*)(aP + k0) : zv8;
        #pragma unroll
        for (int ct = 0; ct < 4; ++ct) {
            int col = col0 + ct * 16 + lrow;
            f16x8 bf = (col < Nc) ? *(const f16x8*)(Btr + (size_t)col * K + lq * 8 + k0) : zv8;
            acc[ct] = __builtin_amdgcn_mfma_f32_16x16x32_f16(af, bf, acc[ct], 0, 0, 0);
        }
    }
    half_t* Zr = Z + (size_t)r * N_ * Nc;
    int rbase = blockIdx.x * 64 + wave * 16 + lq * 4;
    #pragma unroll
    for (int ct = 0; ct < 4; ++ct) {
        int col = col0 + ct * 16 + lrow;
        if (col >= Nc) continue;
        #pragma unroll
        for (int g = 0; g < 4; ++g) {
            int row = rbase + g;
            if (row < M) Zr[(size_t)row * Nc + col] = (half_t)acc[ct][g];
        }
    }
}

// ---------------- attention logits v2: one THREAD per (r,n,h), no shuffles ----
template <int Dd>
__global__ __launch_bounds__(256) void attn2_kernel(
        const half_t* __restrict__ z, const float* __restrict__ al,
        const float* __restrict__ ar, float* __restrict__ el,
        float* __restrict__ er) {
    int t = blockIdx.x * 256 + threadIdx.x;
    if (t >= R_ * N_ * H_) return;
    int rn = t / H_, h = t - rn * H_;
    int r = rn / N_;
    const half_t* zrow = z + (size_t)rn * (3 * Dd) + h * Dd;
    const float* alp = al + (r * H_ + h) * Dd;
    const float* arp = ar + (r * H_ + h) * Dd;
    float p0 = 0.f, p1 = 0.f, q0 = 0.f, q1 = 0.f;
    #pragma unroll
    for (int c = 0; c < Dd / 8; ++c) {
        f16x8 zv = *(const f16x8*)(zrow + c * 8);
        #pragma unroll
        for (int j = 0; j < 8; j += 2) {
            float za = (float)zv[j], zb = (float)zv[j + 1];
            p0 += za * alp[c * 8 + j];
            p1 += zb * alp[c * 8 + j + 1];
            q0 += za * arp[c * 8 + j];
            q1 += zb * arp[c * 8 + j + 1];
        }
    }
    el[t] = p0 + p1;
    er[t] = q0 + q1;
}

// ---------------- fused softmax + gather + aggregate (v7b: one wave per NODE) ---
// Wave owns node n, loops over R=3 relations. Split-wave main loop (2 edges
// per wave instruction, 4-edge unroll, no-max softmax). NOTE: l is REPLICATED
// across lanes of a head group (all compute identical c per edge); after the
// single lane^32 cross-half combine l is complete — NO intra-group reduce
// (round-11 bug). Final: cyclic head-sum + redistribute once, plain coalesced
// store. OutT = half (layer1) or float (layer2/d_out).
template <int Dd, int VEC, bool RELU, typename OutT>
__global__ __launch_bounds__(256) void agg10_kernel(
        const int* __restrict__ rowptr, const int* __restrict__ csr_src,
        const half_t* __restrict__ z, const float* __restrict__ el,
        const float* __restrict__ er, const float* __restrict__ bias,
        OutT* __restrict__ out, float scale) {
    constexpr int ROWH = 3 * Dd;        // halves per z row
    constexpr int LPE  = ROWH / VEC;    // sub-lanes per edge (30 / 24)
    constexpr int PH   = Dd / VEC;      // sub-lanes per head (10 / 8)
    using fv = typename vecT<VEC>::type;
    int n = blockIdx.x * 4 + (threadIdx.x >> 6);
    int lane = threadIdx.x & 63;
    if (n >= N_) return;
    int hf = lane >> 5;                 // half-wave index
    int sub = lane & 31;
    bool act = sub < LPE;
    int hl = act ? sub / PH : 0;
    int dl = act ? sub - hl * PH : 0;
    int zoff = VEC * sub;
    float vacc[VEC] = {};
    #pragma unroll
    for (int r = 0; r < R_; ++r) {
        int start = rowptr[r * (N_ + 1) + n];
        int end   = rowptr[r * (N_ + 1) + n + 1];
        const int* cs = csr_src + (size_t)r * E_;
        const half_t* zr = z + (size_t)r * N_ * ROWH;
        const float* elr = el + (size_t)r * N_ * H_;
        float erv = er[((size_t)r * N_ + n) * H_ + hl];
        float a[VEC] = {};
        float l = 0.f;
        int i = start;
        for (; i + 4 <= end; i += 4) {
            int sA = cs[i + hf], sB = cs[i + 2 + hf];
            int oA = sA * ROWH, oB = sB * ROWH;
            float xA = elr[sA * H_ + hl] + erv;
            float xB = elr[sB * H_ + hl] + erv;
            fv zA = {}, zB = {};
            if (act) {
                zA = *(const fv*)(zr + oA + zoff);
                zB = *(const fv*)(zr + oB + zoff);
            }
            xA = fmaxf(xA, NEG_SLOPE * xA);
            xB = fmaxf(xB, NEG_SLOPE * xB);
            float cA = __expf(xA), cB = __expf(xB);
            l += cA + cB;
            #pragma unroll
            for (int v = 0; v < VEC; ++v)
                a[v] += cA * (float)zA[v] + cB * (float)zB[v];
        }
        for (; i < end; i += 2) {
            int e0 = i + hf;
            bool ok = e0 < end;
            int s0 = ok ? cs[e0] : cs[start];
            int o0 = s0 * ROWH;
            float x = elr[s0 * H_ + hl] + erv;
            fv z0 = {};
            if (act) z0 = *(const fv*)(zr + o0 + zoff);
            x = fmaxf(x, NEG_SLOPE * x);
            float c = ok ? __expf(x) : 0.f;
            l += c;
            #pragma unroll
            for (int v = 0; v < VEC; ++v)
                a[v] += c * (float)z0[v];
        }
        // cross-half combine (VEC+1 independent shuffles) — l complete after this
        #pragma unroll
        for (int v = 0; v < VEC; ++v) a[v] += __shfl(a[v], lane ^ 32);
        l += __shfl(l, lane ^ 32);
        float li = (l > 0.f) ? 1.f / l : 0.f;
        const float* br = bias + r * ROWH + hl * Dd + VEC * dl;
        #pragma unroll
        for (int v = 0; v < VEC; ++v) {
            float t = a[v] * li + br[v];
            if (RELU) t = fmaxf(t, 0.f);
            vacc[v] += t;
        }
    }
    // ---- final head-sum (cyclic within half, exact 3-term) ----
    int base = lane & 32;
    int p1 = sub + PH;     if (p1 >= LPE) p1 -= LPE;
    int p2 = sub + 2 * PH; if (p2 >= LPE) p2 -= LPE;
    #pragma unroll
    for (int v = 0; v < VEC; ++v)
        vacc[v] += __shfl(vacc[v], base + p1) + __shfl(vacc[v], base + p2);
    // ---- redistribute: lane j holds output col j ----
    int srcl = lane / VEC;
    int cm = lane & (VEC - 1);
    float tv[VEC];
    #pragma unroll
    for (int v = 0; v < VEC; ++v) tv[v] = __shfl(vacc[v], srcl);
    float outv = tv[0];
    #pragma unroll
    for (int v = 1; v < VEC; ++v) outv = (cm == v) ? tv[v] : outv;
    if (lane < Dd) out[(size_t)n * Dd + lane] = (OutT)(outv * scale);
}

// ---------------- launch ----------------
static inline size_t align256(size_t x) { return (x + 255) & ~(size_t)255; }

extern "C" void kernel_launch(void* const* d_in, const int* in_sizes, int n_in,
                              void* d_out, int out_size, void* d_ws, size_t ws_size,
                              hipStream_t stream) {
    const float* feat = (const float*)d_in[0];
    const int*   src  = (const int*)d_in[1];
    const int*   dst  = (const int*)d_in[2];
    const float* W1   = (const float*)d_in[3];
    const float* al1  = (const float*)d_in[4];
    const float* ar1  = (const float*)d_in[5];
    const float* b1   = (const float*)d_in[6];
    const float* W2   = (const float*)d_in[7];
    const float* al2  = (const float*)d_in[8];
    const float* ar2  = (const float*)d_in[9];
    const float* b2   = (const float*)d_in[10];
    float* out = (float*)d_out;

    // workspace carve
    char* ws = (char*)d_ws;
    size_t off = 0;
    half_t* zbuf = (half_t*)(ws + off); off += align256((size_t)R_ * N_ * (3 * HID_) * 2);
    half_t* featH = (half_t*)(ws + off); off += align256((size_t)N_ * IN_ * 2);
    half_t* h1h  = (half_t*)(ws + off); off += align256((size_t)N_ * HID_ * 2);
    half_t* W1t  = (half_t*)(ws + off); off += align256((size_t)R_ * (H_ * HID_) * IN_ * 2);
    half_t* W2t  = (half_t*)(ws + off); off += align256((size_t)R_ * (H_ * C_) * HID_ * 2);
    float* el   = (float*)(ws + off); off += align256((size_t)R_ * N_ * H_ * 4);
    float* er   = (float*)(ws + off); off += align256((size_t)R_ * N_ * H_ * 4);
    int* deg    = (int*)(ws + off);   off += align256((size_t)R_ * N_ * 4);
    int* rowptr = (int*)(ws + off);   off += align256((size_t)R_ * (N_ + 1) * 4);
    int* cursor = (int*)(ws + off);   off += align256((size_t)R_ * N_ * 4);
    int* bsum   = (int*)(ws + off);   off += align256((size_t)R_ * NCH2 * 4);
    int* csr    = (int*)(ws + off);   off += align256((size_t)R_ * E_ * 4);
    (void)ws_size; (void)n_in; (void)in_sizes; (void)out_size;

    const int EDGE_BLOCKS = (R_ * E_ + 255) / 256;     // 4688
    const int ROW_TILES = (N_ + 63) / 64;              // 782
    const int NODE_BLOCKS = (R_ * N_ + 255) / 256;     // 586
    const int NODE_WAVES = (N_ + 3) / 4;               // 12500
    const int ATTN_BLOCKS = (R_ * N_ * H_ + 255) / 256;// 1758

    // ---- input casts / weight transposes ----
    cast_f2h_kernel<<<(N_ * IN_ / 4 + 255) / 256, 256, 0, stream>>>(feat, featH, N_ * IN_ / 4);
    transcast_kernel<<<(R_ * IN_ * (H_ * HID_) + 255) / 256, 256, 0, stream>>>(W1, W1t, IN_, H_ * HID_);
    transcast_kernel<<<(R_ * HID_ * (H_ * C_) + 255) / 256, 256, 0, stream>>>(W2, W2t, HID_, H_ * C_);

    // ---- CSR build (shared by both layers) ----
    zero_kernel<<<NODE_BLOCKS, 256, 0, stream>>>((float*)deg, (size_t)R_ * N_);
    hist_kernel<<<EDGE_BLOCKS, 256, 0, stream>>>(dst, deg);
    scanA_kernel<<<dim3(NCH, R_), 256, 0, stream>>>(deg, bsum);
    scanB_kernel<<<1, 64, 0, stream>>>(bsum);
    scanC_kernel<<<dim3(NCH, R_), 256, 0, stream>>>(deg, bsum, rowptr, cursor);
    fill_kernel<<<EDGE_BLOCKS, 256, 0, stream>>>(src, dst, cursor, csr);

    // ---- layer 1: IN -> H*HID, relu; agg writes h1h (fp16) directly ----
    mfma_gemm_kernel<IN_><<<dim3(ROW_TILES, 3, R_), 256, 0, stream>>>(
        featH, W1t, zbuf, N_, H_ * HID_);
    attn2_kernel<HID_><<<ATTN_BLOCKS, 256, 0, stream>>>(zbuf, al1, ar1, el, er);
    agg10_kernel<HID_, 8, true, half_t><<<NODE_WAVES, 256, 0, stream>>>(
        rowptr, csr, zbuf, el, er, b1, h1h, 1.f / (H_ * R_));

    // ---- layer 2: HID -> H*C, no relu; agg writes d_out (fp32) directly ----
    mfma_gemm_kernel<HID_><<<dim3(ROW_TILES, 2, R_), 256, 0, stream>>>(
        h1h, W2t, zbuf, N_, H_ * C_);
    attn2_kernel<C_><<<ATTN_BLOCKS, 256, 0, stream>>>(zbuf, al2, ar2, el, er);
    agg10_kernel<C_, 4, false, float><<<NODE_WAVES, 256, 0, stream>>>(
        rowptr, csr, zbuf, el, er, b2, out, 1.f / (H_ * R_));
}

// Round 13
// 548.950 us; speedup vs baseline: 1.6413x; 1.0450x over previous
//
#include <hip/hip_runtime.h>

// Problem constants (fixed by reference)
#define R_   3
#define N_   50000
#define E_   400000
#define IN_  128
#define HID_ 64
#define C_   40
#define H_   3
#define NEG_SLOPE 0.2f

#define SCAN_CHUNK 1024
#define NCH  49      // ceil(N_/1024)
#define NCH2 64      // padded stride

typedef _Float16 half_t;
typedef _Float16 f16x8 __attribute__((ext_vector_type(8)));
typedef _Float16 f16x4 __attribute__((ext_vector_type(4)));
typedef float float4v __attribute__((ext_vector_type(4)));

template <int V> struct vecT;
template <> struct vecT<4> { typedef f16x4 type; };
template <> struct vecT<8> { typedef f16x8 type; };

// ---------------- utility ----------------
__global__ void zero_kernel(float* __restrict__ p, size_t n) {
    size_t i = (size_t)blockIdx.x * blockDim.x + threadIdx.x;
    if (i < n) p[i] = 0.f;
}

// float -> half, vectorized x4 (n must be divisible by 4)
__global__ void cast_f2h_kernel(const float* __restrict__ in, half_t* __restrict__ outp, int n4) {
    int i = blockIdx.x * 256 + threadIdx.x;
    if (i < n4) {
        float4 v = ((const float4*)in)[i];
        f16x4 h;
        h[0] = (half_t)v.x; h[1] = (half_t)v.y;
        h[2] = (half_t)v.z; h[3] = (half_t)v.w;
        ((f16x4*)outp)[i] = h;
    }
}

// W: [R][K][Nc] fp32 -> Wt: [R][Nc][K] fp16 (tiny matrices)
__global__ void transcast_kernel(const float* __restrict__ W, half_t* __restrict__ Wt,
                                 int K, int Nc) {
    int idx = blockIdx.x * 256 + threadIdx.x;
    int total = R_ * K * Nc;
    if (idx < total) {
        int r = idx / (K * Nc);
        int rem = idx - r * K * Nc;
        int n = rem / K;
        int k = rem - n * K;
        Wt[idx] = (half_t)W[((size_t)r * K + k) * Nc + n];
    }
}

// ---------------- CSR build ----------------
__global__ void hist_kernel(const int* __restrict__ dst, int* __restrict__ deg) {
    int idx = blockIdx.x * 256 + threadIdx.x;
    if (idx < R_ * E_) {
        int r = idx / E_;
        atomicAdd(&deg[r * N_ + dst[idx]], 1);
    }
}

__global__ void scanA_kernel(const int* __restrict__ deg, int* __restrict__ bsum) {
    int r = blockIdx.y, ch = blockIdx.x, tid = threadIdx.x;
    int base = ch * SCAN_CHUNK + tid * 4;
    int s = 0;
    for (int j = 0; j < 4; ++j) {
        int i = base + j;
        if (i < N_) s += deg[r * N_ + i];
    }
    __shared__ int red[256];
    red[tid] = s; __syncthreads();
    for (int off = 128; off; off >>= 1) {
        if (tid < off) red[tid] += red[tid + off];
        __syncthreads();
    }
    if (tid == 0) bsum[r * NCH2 + ch] = red[0];
}

__global__ void scanB_kernel(int* __restrict__ bsum) {
    int t = threadIdx.x;
    if (t < R_) {
        int run = 0;
        for (int c = 0; c < NCH; ++c) {
            int v = bsum[t * NCH2 + c];
            bsum[t * NCH2 + c] = run;
            run += v;
        }
    }
}

__global__ void scanC_kernel(const int* __restrict__ deg, const int* __restrict__ bsum,
                             int* __restrict__ rowptr, int* __restrict__ cursor) {
    int r = blockIdx.y, ch = blockIdx.x, tid = threadIdx.x;
    int base = ch * SCAN_CHUNK + tid * 4;
    int v[4]; int s = 0;
    for (int j = 0; j < 4; ++j) {
        int i = base + j;
        v[j] = (i < N_) ? deg[r * N_ + i] : 0;
        s += v[j];
    }
    __shared__ int buf[256];
    buf[tid] = s; __syncthreads();
    for (int off = 1; off < 256; off <<= 1) {
        int t2 = (tid >= off) ? buf[tid - off] : 0;
        __syncthreads();
        buf[tid] += t2;
        __syncthreads();
    }
    int excl = buf[tid] - s + bsum[r * NCH2 + ch];
    int run = excl;
    for (int j = 0; j < 4; ++j) {
        int i = base + j;
        if (i < N_) {
            rowptr[r * (N_ + 1) + i] = run;
            cursor[r * N_ + i] = run;
            run += v[j];
        }
    }
    if (ch == 0 && tid == 0) rowptr[r * (N_ + 1) + N_] = E_;
}

__global__ void fill_kernel(const int* __restrict__ src, const int* __restrict__ dst,
                            int* __restrict__ cursor, int* __restrict__ csr_src) {
    int idx = blockIdx.x * 256 + threadIdx.x;
    if (idx < R_ * E_) {
        int r = idx / E_;
        int pos = atomicAdd(&cursor[r * N_ + dst[idx]], 1);
        csr_src[(size_t)r * E_ + pos] = src[idx];
    }
}

// ---------------- MFMA GEMM: Z[r] = A @ Bt[r]^T (row stride = Nc) ----------------
template <int K>
__global__ __launch_bounds__(256) void mfma_gemm_kernel(
        const half_t* __restrict__ A, const half_t* __restrict__ Bt,
        half_t* __restrict__ Z, int M, int Nc) {
    int r = blockIdx.z;
    int wave = threadIdx.x >> 6, lane = threadIdx.x & 63;
    int lrow = lane & 15, lq = lane >> 4;
    int rowA = blockIdx.x * 64 + wave * 16 + lrow;
    int col0 = blockIdx.y * 64;
    const half_t* Btr = Bt + (size_t)r * Nc * K;
    const half_t* aP = A + (size_t)rowA * K + lq * 8;
    bool arow_ok = (rowA < M);
    f16x8 zv8 = {};
    float4v acc[4] = {};
    #pragma unroll
    for (int k0 = 0; k0 < K; k0 += 32) {
        f16x8 af = arow_ok ? *(const f16x8*)(aP + k0) : zv8;
        #pragma unroll
        for (int ct = 0; ct < 4; ++ct) {
            int col = col0 + ct * 16 + lrow;
            f16x8 bf = (col < Nc) ? *(const f16x8*)(Btr + (size_t)col * K + lq * 8 + k0) : zv8;
            acc[ct] = __builtin_amdgcn_mfma_f32_16x16x32_f16(af, bf, acc[ct], 0, 0, 0);
        }
    }
    half_t* Zr = Z + (size_t)r * N_ * Nc;
    int rbase = blockIdx.x * 64 + wave * 16 + lq * 4;
    #pragma unroll
    for (int ct = 0; ct < 4; ++ct) {
        int col = col0 + ct * 16 + lrow;
        if (col >= Nc) continue;
        #pragma unroll
        for (int g = 0; g < 4; ++g) {
            int row = rbase + g;
            if (row < M) Zr[(size_t)row * Nc + col] = (half_t)acc[ct][g];
        }
    }
}

// ---------------- attention logits v2: one THREAD per (r,n,h), no shuffles ----
template <int Dd>
__global__ __launch_bounds__(256) void attn2_kernel(
        const half_t* __restrict__ z, const float* __restrict__ al,
        const float* __restrict__ ar, float* __restrict__ el,
        float* __restrict__ er) {
    int t = blockIdx.x * 256 + threadIdx.x;
    if (t >= R_ * N_ * H_) return;
    int rn = t / H_, h = t - rn * H_;
    int r = rn / N_;
    const half_t* zrow = z + (size_t)rn * (3 * Dd) + h * Dd;
    const float* alp = al + (r * H_ + h) * Dd;
    const float* arp = ar + (r * H_ + h) * Dd;
    float p0 = 0.f, p1 = 0.f, q0 = 0.f, q1 = 0.f;
    #pragma unroll
    for (int c = 0; c < Dd / 8; ++c) {
        f16x8 zv = *(const f16x8*)(zrow + c * 8);
        #pragma unroll
        for (int j = 0; j < 8; j += 2) {
            float za = (float)zv[j], zb = (float)zv[j + 1];
            p0 += za * alp[c * 8 + j];
            p1 += zb * alp[c * 8 + j + 1];
            q0 += za * arp[c * 8 + j];
            q1 += zb * arp[c * 8 + j + 1];
        }
    }
    el[t] = p0 + p1;
    er[t] = q0 + q1;
}

// ---------------- fused softmax + gather + aggregate (v8: relations interleaved) -
// One wave per node. Merged loop: each iteration issues loads (csr -> el + z)
// for up to 4 edges of ALL THREE relations back-to-back (~18 independent loads
// in flight), then the three FMA blocks. Per-edge guards (c=0, clamped safe
// address) keep the loop uniform; trip count = max(ceil(deg_r/4)) instead of
// the serial sum. ALL cross-lane combines hoisted to the epilogue (27
// independent shuffles, pipelined). l is replicated per head group — only the
// lane^32 combine (round-11 lesson). Plain coalesced store.
template <int Dd, int VEC, bool RELU, typename OutT>
__global__ __launch_bounds__(256) void agg11_kernel(
        const int* __restrict__ rowptr, const int* __restrict__ csr_src,
        const half_t* __restrict__ z, const float* __restrict__ el,
        const float* __restrict__ er, const float* __restrict__ bias,
        OutT* __restrict__ out, float scale) {
    constexpr int ROWH = 3 * Dd;        // halves per z row
    constexpr int LPE  = ROWH / VEC;    // sub-lanes per edge (30 / 24)
    constexpr int PH   = Dd / VEC;      // sub-lanes per head (10 / 8)
    using fv = typename vecT<VEC>::type;
    int n = blockIdx.x * 4 + (threadIdx.x >> 6);
    int lane = threadIdx.x & 63;
    if (n >= N_) return;
    int hf = lane >> 5;                 // half-wave index
    int sub = lane & 31;
    bool act = sub < LPE;
    int hl = act ? sub / PH : 0;
    int dl = act ? sub - hl * PH : 0;
    int zoff = VEC * sub;
    // ---- prologue: all relations' bounds + erv (independent loads) ----
    int ii[R_], ee[R_];
    float ervv[R_];
    #pragma unroll
    for (int r = 0; r < R_; ++r) {
        ii[r] = rowptr[r * (N_ + 1) + n];
        ee[r] = rowptr[r * (N_ + 1) + n + 1];
        ervv[r] = er[((size_t)r * N_ + n) * H_ + hl];
    }
    float aa[R_][VEC] = {};
    float ll[R_] = {};
    // ---- merged loop: 4 edges per relation per iteration ----
    while (ii[0] < ee[0] || ii[1] < ee[1] || ii[2] < ee[2]) {
        fv zA[R_], zB[R_];
        float xA[R_], xB[R_];
        bool okA[R_], okB[R_];
        #pragma unroll
        for (int r = 0; r < R_; ++r) {
            const int* cs = csr_src + (size_t)r * E_;
            const half_t* zr = z + (size_t)r * N_ * ROWH;
            const float* elr = el + (size_t)r * N_ * H_;
            int eA = ii[r] + hf, eB = ii[r] + 2 + hf;
            okA[r] = eA < ee[r];
            okB[r] = eB < ee[r];
            int sA = cs[okA[r] ? eA : 0];
            int sB = cs[okB[r] ? eB : 0];
            xA[r] = elr[sA * H_ + hl] + ervv[r];
            xB[r] = elr[sB * H_ + hl] + ervv[r];
            zA[r] = {}; zB[r] = {};
            if (act) {
                zA[r] = *(const fv*)(zr + sA * ROWH + zoff);
                zB[r] = *(const fv*)(zr + sB * ROWH + zoff);
            }
        }
        #pragma unroll
        for (int r = 0; r < R_; ++r) {
            float xa = xA[r]; xa = fmaxf(xa, NEG_SLOPE * xa);
            float xb = xB[r]; xb = fmaxf(xb, NEG_SLOPE * xb);
            float cA = okA[r] ? __expf(xa) : 0.f;
            float cB = okB[r] ? __expf(xb) : 0.f;
            ll[r] += cA + cB;
            #pragma unroll
            for (int v = 0; v < VEC; ++v)
                aa[r][v] += cA * (float)zA[r][v] + cB * (float)zB[r][v];
        }
        #pragma unroll
        for (int r = 0; r < R_; ++r) ii[r] += 4;
    }
    // ---- epilogue: cross-half combines (all independent, pipelined) ----
    #pragma unroll
    for (int r = 0; r < R_; ++r) {
        #pragma unroll
        for (int v = 0; v < VEC; ++v) aa[r][v] += __shfl(aa[r][v], lane ^ 32);
        ll[r] += __shfl(ll[r], lane ^ 32);
    }
    float vacc[VEC] = {};
    #pragma unroll
    for (int r = 0; r < R_; ++r) {
        float li = (ll[r] > 0.f) ? 1.f / ll[r] : 0.f;
        const float* br = bias + r * ROWH + hl * Dd + VEC * dl;
        #pragma unroll
        for (int v = 0; v < VEC; ++v) {
            float t = aa[r][v] * li + br[v];
            if (RELU) t = fmaxf(t, 0.f);
            vacc[v] += t;
        }
    }
    // ---- final head-sum (cyclic within half, exact 3-term) ----
    int base = lane & 32;
    int p1 = sub + PH;     if (p1 >= LPE) p1 -= LPE;
    int p2 = sub + 2 * PH; if (p2 >= LPE) p2 -= LPE;
    #pragma unroll
    for (int v = 0; v < VEC; ++v)
        vacc[v] += __shfl(vacc[v], base + p1) + __shfl(vacc[v], base + p2);
    // ---- redistribute: lane j holds output col j ----
    int srcl = lane / VEC;
    int cm = lane & (VEC - 1);
    float tv[VEC];
    #pragma unroll
    for (int v = 0; v < VEC; ++v) tv[v] = __shfl(vacc[v], srcl);
    float outv = tv[0];
    #pragma unroll
    for (int v = 1; v < VEC; ++v) outv = (cm == v) ? tv[v] : outv;
    if (lane < Dd) out[(size_t)n * Dd + lane] = (OutT)(outv * scale);
}

// ---------------- launch ----------------
static inline size_t align256(size_t x) { return (x + 255) & ~(size_t)255; }

extern "C" void kernel_launch(void* const* d_in, const int* in_sizes, int n_in,
                              void* d_out, int out_size, void* d_ws, size_t ws_size,
                              hipStream_t stream) {
    const float* feat = (const float*)d_in[0];
    const int*   src  = (const int*)d_in[1];
    const int*   dst  = (const int*)d_in[2];
    const float* W1   = (const float*)d_in[3];
    const float* al1  = (const float*)d_in[4];
    const float* ar1  = (const float*)d_in[5];
    const float* b1   = (const float*)d_in[6];
    const float* W2   = (const float*)d_in[7];
    const float* al2  = (const float*)d_in[8];
    const float* ar2  = (const float*)d_in[9];
    const float* b2   = (const float*)d_in[10];
    float* out = (float*)d_out;

    // workspace carve
    char* ws = (char*)d_ws;
    size_t off = 0;
    half_t* zbuf = (half_t*)(ws + off); off += align256((size_t)R_ * N_ * (3 * HID_) * 2);
    half_t* featH = (half_t*)(ws + off); off += align256((size_t)N_ * IN_ * 2);
    half_t* h1h  = (half_t*)(ws + off); off += align256((size_t)N_ * HID_ * 2);
    half_t* W1t  = (half_t*)(ws + off); off += align256((size_t)R_ * (H_ * HID_) * IN_ * 2);
    half_t* W2t  = (half_t*)(ws + off); off += align256((size_t)R_ * (H_ * C_) * HID_ * 2);
    float* el   = (float*)(ws + off); off += align256((size_t)R_ * N_ * H_ * 4);
    float* er   = (float*)(ws + off); off += align256((size_t)R_ * N_ * H_ * 4);
    int* deg    = (int*)(ws + off);   off += align256((size_t)R_ * N_ * 4);
    int* rowptr = (int*)(ws + off);   off += align256((size_t)R_ * (N_ + 1) * 4);
    int* cursor = (int*)(ws + off);   off += align256((size_t)R_ * N_ * 4);
    int* bsum   = (int*)(ws + off);   off += align256((size_t)R_ * NCH2 * 4);
    int* csr    = (int*)(ws + off);   off += align256((size_t)R_ * E_ * 4);
    (void)ws_size; (void)n_in; (void)in_sizes; (void)out_size;

    const int EDGE_BLOCKS = (R_ * E_ + 255) / 256;     // 4688
    const int ROW_TILES = (N_ + 63) / 64;              // 782
    const int NODE_BLOCKS = (R_ * N_ + 255) / 256;     // 586
    const int NODE_WAVES = (N_ + 3) / 4;               // 12500
    const int ATTN_BLOCKS = (R_ * N_ * H_ + 255) / 256;// 1758

    // ---- input casts / weight transposes ----
    cast_f2h_kernel<<<(N_ * IN_ / 4 + 255) / 256, 256, 0, stream>>>(feat, featH, N_ * IN_ / 4);
    transcast_kernel<<<(R_ * IN_ * (H_ * HID_) + 255) / 256, 256, 0, stream>>>(W1, W1t, IN_, H_ * HID_);
    transcast_kernel<<<(R_ * HID_ * (H_ * C_) + 255) / 256, 256, 0, stream>>>(W2, W2t, HID_, H_ * C_);

    // ---- CSR build (shared by both layers) ----
    zero_kernel<<<NODE_BLOCKS, 256, 0, stream>>>((float*)deg, (size_t)R_ * N_);
    hist_kernel<<<EDGE_BLOCKS, 256, 0, stream>>>(dst, deg);
    scanA_kernel<<<dim3(NCH, R_), 256, 0, stream>>>(deg, bsum);
    scanB_kernel<<<1, 64, 0, stream>>>(bsum);
    scanC_kernel<<<dim3(NCH, R_), 256, 0, stream>>>(deg, bsum, rowptr, cursor);
    fill_kernel<<<EDGE_BLOCKS, 256, 0, stream>>>(src, dst, cursor, csr);

    // ---- layer 1: IN -> H*HID, relu; agg writes h1h (fp16) directly ----
    mfma_gemm_kernel<IN_><<<dim3(ROW_TILES, 3, R_), 256, 0, stream>>>(
        featH, W1t, zbuf, N_, H_ * HID_);
    attn2_kernel<HID_><<<ATTN_BLOCKS, 256, 0, stream>>>(zbuf, al1, ar1, el, er);
    agg11_kernel<HID_, 8, true, half_t><<<NODE_WAVES, 256, 0, stream>>>(
        rowptr, csr, zbuf, el, er, b1, h1h, 1.f / (H_ * R_));

    // ---- layer 2: HID -> H*C, no relu; agg writes d_out (fp32) directly ----
    mfma_gemm_kernel<HID_><<<dim3(ROW_TILES, 2, R_), 256, 0, stream>>>(
        h1h, W2t, zbuf, N_, H_ * C_);
    attn2_kernel<C_><<<ATTN_BLOCKS, 256, 0, stream>>>(zbuf, al2, ar2, el, er);
    agg11_kernel<C_, 4, false, float><<<NODE_WAVES, 256, 0, stream>>>(
        rowptr, csr, zbuf, el, er, b2, out, 1.f / (H_ * R_));
}

// Round 14
// 534.836 us; speedup vs baseline: 1.6846x; 1.0264x over previous
//
#include <hip/hip_runtime.h>

// Problem constants (fixed by reference)
#define R_   3
#define N_   50000
#define E_   400000
#define IN_  128
#define HID_ 64
#define C_   40
#define H_   3
#define NEG_SLOPE 0.2f

#define SCAN_CHUNK 1024
#define NCH  49      // ceil(N_/1024)
#define NCH2 64      // padded stride

typedef _Float16 half_t;
typedef _Float16 f16x8 __attribute__((ext_vector_type(8)));
typedef _Float16 f16x4 __attribute__((ext_vector_type(4)));
typedef float float4v __attribute__((ext_vector_type(4)));

template <int V> struct vecT;
template <> struct vecT<4> { typedef f16x4 type; };
template <> struct vecT<8> { typedef f16x8 type; };

// ---------------- utility ----------------
__global__ void zero_kernel(float* __restrict__ p, size_t n) {
    size_t i = (size_t)blockIdx.x * blockDim.x + threadIdx.x;
    if (i < n) p[i] = 0.f;
}

// float -> half, vectorized x4 (n must be divisible by 4)
__global__ void cast_f2h_kernel(const float* __restrict__ in, half_t* __restrict__ outp, int n4) {
    int i = blockIdx.x * 256 + threadIdx.x;
    if (i < n4) {
        float4 v = ((const float4*)in)[i];
        f16x4 h;
        h[0] = (half_t)v.x; h[1] = (half_t)v.y;
        h[2] = (half_t)v.z; h[3] = (half_t)v.w;
        ((f16x4*)outp)[i] = h;
    }
}

// W: [R][K][Nc] fp32 -> Wt: [R][Nc][K] fp16 (tiny matrices)
__global__ void transcast_kernel(const float* __restrict__ W, half_t* __restrict__ Wt,
                                 int K, int Nc) {
    int idx = blockIdx.x * 256 + threadIdx.x;
    int total = R_ * K * Nc;
    if (idx < total) {
        int r = idx / (K * Nc);
        int rem = idx - r * K * Nc;
        int n = rem / K;
        int k = rem - n * K;
        Wt[idx] = (half_t)W[((size_t)r * K + k) * Nc + n];
    }
}

// ---------------- CSR build ----------------
__global__ void hist_kernel(const int* __restrict__ dst, int* __restrict__ deg) {
    int idx = blockIdx.x * 256 + threadIdx.x;
    if (idx < R_ * E_) {
        int r = idx / E_;
        atomicAdd(&deg[r * N_ + dst[idx]], 1);
    }
}

__global__ void scanA_kernel(const int* __restrict__ deg, int* __restrict__ bsum) {
    int r = blockIdx.y, ch = blockIdx.x, tid = threadIdx.x;
    int base = ch * SCAN_CHUNK + tid * 4;
    int s = 0;
    for (int j = 0; j < 4; ++j) {
        int i = base + j;
        if (i < N_) s += deg[r * N_ + i];
    }
    __shared__ int red[256];
    red[tid] = s; __syncthreads();
    for (int off = 128; off; off >>= 1) {
        if (tid < off) red[tid] += red[tid + off];
        __syncthreads();
    }
    if (tid == 0) bsum[r * NCH2 + ch] = red[0];
}

__global__ void scanB_kernel(int* __restrict__ bsum) {
    int t = threadIdx.x;
    if (t < R_) {
        int run = 0;
        for (int c = 0; c < NCH; ++c) {
            int v = bsum[t * NCH2 + c];
            bsum[t * NCH2 + c] = run;
            run += v;
        }
    }
}

__global__ void scanC_kernel(const int* __restrict__ deg, const int* __restrict__ bsum,
                             int* __restrict__ rowptr, int* __restrict__ cursor) {
    int r = blockIdx.y, ch = blockIdx.x, tid = threadIdx.x;
    int base = ch * SCAN_CHUNK + tid * 4;
    int v[4]; int s = 0;
    for (int j = 0; j < 4; ++j) {
        int i = base + j;
        v[j] = (i < N_) ? deg[r * N_ + i] : 0;
        s += v[j];
    }
    __shared__ int buf[256];
    buf[tid] = s; __syncthreads();
    for (int off = 1; off < 256; off <<= 1) {
        int t2 = (tid >= off) ? buf[tid - off] : 0;
        __syncthreads();
        buf[tid] += t2;
        __syncthreads();
    }
    int excl = buf[tid] - s + bsum[r * NCH2 + ch];
    int run = excl;
    for (int j = 0; j < 4; ++j) {
        int i = base + j;
        if (i < N_) {
            rowptr[r * (N_ + 1) + i] = run;
            cursor[r * N_ + i] = run;
            run += v[j];
        }
    }
    if (ch == 0 && tid == 0) rowptr[r * (N_ + 1) + N_] = E_;
}

__global__ void fill_kernel(const int* __restrict__ src, const int* __restrict__ dst,
                            int* __restrict__ cursor, int* __restrict__ csr_src) {
    int idx = blockIdx.x * 256 + threadIdx.x;
    if (idx < R_ * E_) {
        int r = idx / E_;
        int pos = atomicAdd(&cursor[r * N_ + dst[idx]], 1);
        csr_src[(size_t)r * E_ + pos] = src[idx];
    }
}

// ---------------- MFMA GEMM: Z[r] = A @ Bt[r]^T (row stride = Nc) ----------------
template <int K>
__global__ __launch_bounds__(256) void mfma_gemm_kernel(
        const half_t* __restrict__ A, const half_t* __restrict__ Bt,
        half_t* __restrict__ Z, int M, int Nc) {
    int r = blockIdx.z;
    int wave = threadIdx.x >> 6, lane = threadIdx.x & 63;
    int lrow = lane & 15, lq = lane >> 4;
    int rowA = blockIdx.x * 64 + wave * 16 + lrow;
    int col0 = blockIdx.y * 64;
    const half_t* Btr = Bt + (size_t)r * Nc * K;
    const half_t* aP = A + (size_t)rowA * K + lq * 8;
    bool arow_ok = (rowA < M);
    f16x8 zv8 = {};
    float4v acc[4] = {};
    #pragma unroll
    for (int k0 = 0; k0 < K; k0 += 32) {
        f16x8 af = arow_ok ? *(const f16x8*)(aP + k0) : zv8;
        #pragma unroll
        for (int ct = 0; ct < 4; ++ct) {
            int col = col0 + ct * 16 + lrow;
            f16x8 bf = (col < Nc) ? *(const f16x8*)(Btr + (size_t)col * K + lq * 8 + k0) : zv8;
            acc[ct] = __builtin_amdgcn_mfma_f32_16x16x32_f16(af, bf, acc[ct], 0, 0, 0);
        }
    }
    half_t* Zr = Z + (size_t)r * N_ * Nc;
    int rbase = blockIdx.x * 64 + wave * 16 + lq * 4;
    #pragma unroll
    for (int ct = 0; ct < 4; ++ct) {
        int col = col0 + ct * 16 + lrow;
        if (col >= Nc) continue;
        #pragma unroll
        for (int g = 0; g < 4; ++g) {
            int row = rbase + g;
            if (row < M) Zr[(size_t)row * Nc + col] = (half_t)acc[ct][g];
        }
    }
}

// ---------------- attention logits v2: one THREAD per (r,n,h), no shuffles ----
template <int Dd>
__global__ __launch_bounds__(256) void attn2_kernel(
        const half_t* __restrict__ z, const float* __restrict__ al,
        const float* __restrict__ ar, float* __restrict__ el,
        float* __restrict__ er) {
    int t = blockIdx.x * 256 + threadIdx.x;
    if (t >= R_ * N_ * H_) return;
    int rn = t / H_, h = t - rn * H_;
    int r = rn / N_;
    const half_t* zrow = z + (size_t)rn * (3 * Dd) + h * Dd;
    const float* alp = al + (r * H_ + h) * Dd;
    const float* arp = ar + (r * H_ + h) * Dd;
    float p0 = 0.f, p1 = 0.f, q0 = 0.f, q1 = 0.f;
    #pragma unroll
    for (int c = 0; c < Dd / 8; ++c) {
        f16x8 zv = *(const f16x8*)(zrow + c * 8);
        #pragma unroll
        for (int j = 0; j < 8; j += 2) {
            float za = (float)zv[j], zb = (float)zv[j + 1];
            p0 += za * alp[c * 8 + j];
            p1 += zb * alp[c * 8 + j + 1];
            q0 += za * arp[c * 8 + j];
            q1 += zb * arp[c * 8 + j + 1];
        }
    }
    el[t] = p0 + p1;
    er[t] = q0 + q1;
}

// ---------------- fused softmax + gather + aggregate (v9: fp16 packed accum) ----
// agg11 structure (one wave per node, 3 relations interleaved, split-wave,
// no-max softmax) with the inner accumulation in PACKED FP16 (v_pk_fma_f16):
// ah += splat(c)*zA + splat(c)*zB — 2 elements/instr, no cvt in-loop. One
// fp32 conversion per element in the epilogue. l stays fp32. Overflow-safe:
// c <= exp(~8) ~ 3e3, |a| <= ~1e4 << 65504. Cross-lane combines hoisted and
// independent; l replicated per head group (only lane^32 combine). Plain
// coalesced store.
template <int Dd, int VEC, bool RELU, typename OutT>
__global__ __launch_bounds__(256) void agg12_kernel(
        const int* __restrict__ rowptr, const int* __restrict__ csr_src,
        const half_t* __restrict__ z, const float* __restrict__ el,
        const float* __restrict__ er, const float* __restrict__ bias,
        OutT* __restrict__ out, float scale) {
    constexpr int ROWH = 3 * Dd;        // halves per z row
    constexpr int LPE  = ROWH / VEC;    // sub-lanes per edge (30 / 24)
    constexpr int PH   = Dd / VEC;      // sub-lanes per head (10 / 8)
    using fv = typename vecT<VEC>::type;
    int n = blockIdx.x * 4 + (threadIdx.x >> 6);
    int lane = threadIdx.x & 63;
    if (n >= N_) return;
    int hf = lane >> 5;                 // half-wave index
    int sub = lane & 31;
    bool act = sub < LPE;
    int hl = act ? sub / PH : 0;
    int dl = act ? sub - hl * PH : 0;
    int zoff = VEC * sub;
    // ---- prologue: all relations' bounds + erv (independent loads) ----
    int ii[R_], ee[R_];
    float ervv[R_];
    #pragma unroll
    for (int r = 0; r < R_; ++r) {
        ii[r] = rowptr[r * (N_ + 1) + n];
        ee[r] = rowptr[r * (N_ + 1) + n + 1];
        ervv[r] = er[((size_t)r * N_ + n) * H_ + hl];
    }
    fv ah[R_] = {};                     // fp16 packed accumulators
    float ll[R_] = {};
    // ---- merged loop: 4 edges per relation per iteration ----
    while (ii[0] < ee[0] || ii[1] < ee[1] || ii[2] < ee[2]) {
        fv zA[R_], zB[R_];
        float xA[R_], xB[R_];
        bool okA[R_], okB[R_];
        #pragma unroll
        for (int r = 0; r < R_; ++r) {
            const int* cs = csr_src + (size_t)r * E_;
            const half_t* zr = z + (size_t)r * N_ * ROWH;
            const float* elr = el + (size_t)r * N_ * H_;
            int eA = ii[r] + hf, eB = ii[r] + 2 + hf;
            okA[r] = eA < ee[r];
            okB[r] = eB < ee[r];
            int sA = cs[okA[r] ? eA : 0];
            int sB = cs[okB[r] ? eB : 0];
            xA[r] = elr[sA * H_ + hl] + ervv[r];
            xB[r] = elr[sB * H_ + hl] + ervv[r];
            zA[r] = {}; zB[r] = {};
            if (act) {
                zA[r] = *(const fv*)(zr + sA * ROWH + zoff);
                zB[r] = *(const fv*)(zr + sB * ROWH + zoff);
            }
        }
        #pragma unroll
        for (int r = 0; r < R_; ++r) {
            float xa = xA[r]; xa = fmaxf(xa, NEG_SLOPE * xa);
            float xb = xB[r]; xb = fmaxf(xb, NEG_SLOPE * xb);
            float cA = okA[r] ? __expf(xa) : 0.f;
            float cB = okB[r] ? __expf(xb) : 0.f;
            ll[r] += cA + cB;
            half_t hA = (half_t)cA, hB = (half_t)cB;
            fv vA, vB;
            #pragma unroll
            for (int v = 0; v < VEC; ++v) { vA[v] = hA; vB[v] = hB; }
            ah[r] += vA * zA[r] + vB * zB[r];   // v_pk_fma_f16
        }
        #pragma unroll
        for (int r = 0; r < R_; ++r) ii[r] += 4;
    }
    // ---- epilogue: convert to fp32 once, then cross-half combines ----
    float aa[R_][VEC];
    #pragma unroll
    for (int r = 0; r < R_; ++r)
        #pragma unroll
        for (int v = 0; v < VEC; ++v) aa[r][v] = (float)ah[r][v];
    #pragma unroll
    for (int r = 0; r < R_; ++r) {
        #pragma unroll
        for (int v = 0; v < VEC; ++v) aa[r][v] += __shfl(aa[r][v], lane ^ 32);
        ll[r] += __shfl(ll[r], lane ^ 32);
    }
    float vacc[VEC] = {};
    #pragma unroll
    for (int r = 0; r < R_; ++r) {
        float li = (ll[r] > 0.f) ? 1.f / ll[r] : 0.f;
        const float* br = bias + r * ROWH + hl * Dd + VEC * dl;
        #pragma unroll
        for (int v = 0; v < VEC; ++v) {
            float t = aa[r][v] * li + br[v];
            if (RELU) t = fmaxf(t, 0.f);
            vacc[v] += t;
        }
    }
    // ---- final head-sum (cyclic within half, exact 3-term) ----
    int base = lane & 32;
    int p1 = sub + PH;     if (p1 >= LPE) p1 -= LPE;
    int p2 = sub + 2 * PH; if (p2 >= LPE) p2 -= LPE;
    #pragma unroll
    for (int v = 0; v < VEC; ++v)
        vacc[v] += __shfl(vacc[v], base + p1) + __shfl(vacc[v], base + p2);
    // ---- redistribute: lane j holds output col j ----
    int srcl = lane / VEC;
    int cm = lane & (VEC - 1);
    float tv[VEC];
    #pragma unroll
    for (int v = 0; v < VEC; ++v) tv[v] = __shfl(vacc[v], srcl);
    float outv = tv[0];
    #pragma unroll
    for (int v = 1; v < VEC; ++v) outv = (cm == v) ? tv[v] : outv;
    if (lane < Dd) out[(size_t)n * Dd + lane] = (OutT)(outv * scale);
}

// ---------------- launch ----------------
static inline size_t align256(size_t x) { return (x + 255) & ~(size_t)255; }

extern "C" void kernel_launch(void* const* d_in, const int* in_sizes, int n_in,
                              void* d_out, int out_size, void* d_ws, size_t ws_size,
                              hipStream_t stream) {
    const float* feat = (const float*)d_in[0];
    const int*   src  = (const int*)d_in[1];
    const int*   dst  = (const int*)d_in[2];
    const float* W1   = (const float*)d_in[3];
    const float* al1  = (const float*)d_in[4];
    const float* ar1  = (const float*)d_in[5];
    const float* b1   = (const float*)d_in[6];
    const float* W2   = (const float*)d_in[7];
    const float* al2  = (const float*)d_in[8];
    const float* ar2  = (const float*)d_in[9];
    const float* b2   = (const float*)d_in[10];
    float* out = (float*)d_out;

    // workspace carve
    char* ws = (char*)d_ws;
    size_t off = 0;
    half_t* zbuf = (half_t*)(ws + off); off += align256((size_t)R_ * N_ * (3 * HID_) * 2);
    half_t* featH = (half_t*)(ws + off); off += align256((size_t)N_ * IN_ * 2);
    half_t* h1h  = (half_t*)(ws + off); off += align256((size_t)N_ * HID_ * 2);
    half_t* W1t  = (half_t*)(ws + off); off += align256((size_t)R_ * (H_ * HID_) * IN_ * 2);
    half_t* W2t  = (half_t*)(ws + off); off += align256((size_t)R_ * (H_ * C_) * HID_ * 2);
    float* el   = (float*)(ws + off); off += align256((size_t)R_ * N_ * H_ * 4);
    float* er   = (float*)(ws + off); off += align256((size_t)R_ * N_ * H_ * 4);
    int* deg    = (int*)(ws + off);   off += align256((size_t)R_ * N_ * 4);
    int* rowptr = (int*)(ws + off);   off += align256((size_t)R_ * (N_ + 1) * 4);
    int* cursor = (int*)(ws + off);   off += align256((size_t)R_ * N_ * 4);
    int* bsum   = (int*)(ws + off);   off += align256((size_t)R_ * NCH2 * 4);
    int* csr    = (int*)(ws + off);   off += align256((size_t)R_ * E_ * 4);
    (void)ws_size; (void)n_in; (void)in_sizes; (void)out_size;

    const int EDGE_BLOCKS = (R_ * E_ + 255) / 256;     // 4688
    const int ROW_TILES = (N_ + 63) / 64;              // 782
    const int NODE_BLOCKS = (R_ * N_ + 255) / 256;     // 586
    const int NODE_WAVES = (N_ + 3) / 4;               // 12500
    const int ATTN_BLOCKS = (R_ * N_ * H_ + 255) / 256;// 1758

    // ---- input casts / weight transposes ----
    cast_f2h_kernel<<<(N_ * IN_ / 4 + 255) / 256, 256, 0, stream>>>(feat, featH, N_ * IN_ / 4);
    transcast_kernel<<<(R_ * IN_ * (H_ * HID_) + 255) / 256, 256, 0, stream>>>(W1, W1t, IN_, H_ * HID_);
    transcast_kernel<<<(R_ * HID_ * (H_ * C_) + 255) / 256, 256, 0, stream>>>(W2, W2t, HID_, H_ * C_);

    // ---- CSR build (shared by both layers) ----
    zero_kernel<<<NODE_BLOCKS, 256, 0, stream>>>((float*)deg, (size_t)R_ * N_);
    hist_kernel<<<EDGE_BLOCKS, 256, 0, stream>>>(dst, deg);
    scanA_kernel<<<dim3(NCH, R_), 256, 0, stream>>>(deg, bsum);
    scanB_kernel<<<1, 64, 0, stream>>>(bsum);
    scanC_kernel<<<dim3(NCH, R_), 256, 0, stream>>>(deg, bsum, rowptr, cursor);
    fill_kernel<<<EDGE_BLOCKS, 256, 0, stream>>>(src, dst, cursor, csr);

    // ---- layer 1: IN -> H*HID, relu; agg writes h1h (fp16) directly ----
    mfma_gemm_kernel<IN_><<<dim3(ROW_TILES, 3, R_), 256, 0, stream>>>(
        featH, W1t, zbuf, N_, H_ * HID_);
    attn2_kernel<HID_><<<ATTN_BLOCKS, 256, 0, stream>>>(zbuf, al1, ar1, el, er);
    agg12_kernel<HID_, 8, true, half_t><<<NODE_WAVES, 256, 0, stream>>>(
        rowptr, csr, zbuf, el, er, b1, h1h, 1.f / (H_ * R_));

    // ---- layer 2: HID -> H*C, no relu; agg writes d_out (fp32) directly ----
    mfma_gemm_kernel<HID_><<<dim3(ROW_TILES, 2, R_), 256, 0, stream>>>(
        h1h, W2t, zbuf, N_, H_ * C_);
    attn2_kernel<C_><<<ATTN_BLOCKS, 256, 0, stream>>>(zbuf, al2, ar2, el, er);
    agg12_kernel<C_, 4, false, float><<<NODE_WAVES, 256, 0, stream>>>(
        rowptr, csr, zbuf, el, er, b2, out, 1.f / (H_ * R_));
}